// Round 1
// baseline (132.559 us; speedup 1.0000x reference)
//
#include <hip/hip_runtime.h>
#include <cstdint>
#include <cstddef>

// Problem constants (match reference file)
#define BB 4
#define MM 8192
#define NN 6890
#define NSEG 16
#define SEGN 431          // ceil(6890/16); last segment has 425
#define CHUNKS 8          // MM / MQ
#define MQ 1024           // queries per nn block
#define QT 4              // queries per thread
#define TPB 256

static constexpr float MIN_T2 = 0.005f * 0.005f;   // MIN_DIST_THRESH^2

// ws layout (bytes):
//   [0, 440960)          float4 cand[BB*NN]  (x,y,z, s2 or +inf if invalid)
//   [441344, 703488)     u64 packed[BB*MM]   (d2_bits<<32 | idx), atomicMin
//   [703488, 704000)     float blockSums[128]
//   [704000, 704512)     int   blockMatch[128]
#define OFF_PACKED 441344
#define OFF_BSUMS  703488
#define OFF_BMATCH 704000

// Kernel 1: build packed candidates (v_template + valid mask + |s|^2),
// and init the packed argmin array to all-ones (u64 max).
__global__ __launch_bounds__(256) void prep_kernel(
    const float* __restrict__ vt, const int* __restrict__ valid,
    float4* __restrict__ cand, unsigned long long* __restrict__ packed)
{
    int i = blockIdx.x * 256 + threadIdx.x;   // grid covers 32768 >= BB*NN
    if (i < BB * MM) packed[i] = ~0ULL;
    if (i < BB * NN) {
        const float* p = vt + (size_t)i * 3;
        float x = p[0], y = p[1], z = p[2];
        float s2 = x * x + y * y + z * z;
        if (valid[i] <= 0) s2 = __builtin_inff();
        cand[i] = make_float4(x, y, z, s2);
    }
}

// Kernel 2: brute-force NN over one (batch, m-chunk, n-segment) per block.
// Each thread owns QT queries; candidates broadcast from LDS.
__global__ __launch_bounds__(TPB) void nn_kernel(
    const float* __restrict__ cloth, const float4* __restrict__ cand,
    unsigned long long* __restrict__ packed)
{
    __shared__ float4 lds[SEGN];
    int bid   = blockIdx.x;            // 512 blocks
    int seg   = bid & (NSEG - 1);
    int chunk = (bid >> 4) & (CHUNKS - 1);
    int b     = bid >> 7;
    int n0    = seg * SEGN;
    int segn  = (NN - n0 < SEGN) ? (NN - n0) : SEGN;

    for (int i = threadIdx.x; i < segn; i += TPB)
        lds[i] = cand[b * NN + n0 + i];

    float qx[QT], qy[QT], qz[QT], qc2[QT], bd[QT];
    int bi[QT];
    int m0 = chunk * MQ + threadIdx.x;
#pragma unroll
    for (int j = 0; j < QT; j++) {
        int m = m0 + j * TPB;
        const float* p = cloth + ((size_t)b * MM + m) * 3;
        float x = p[0], y = p[1], z = p[2];
        qx[j] = x; qy[j] = y; qz[j] = z;
        qc2[j] = x * x + y * y + z * z;
        bd[j] = __builtin_inff();
        bi[j] = 0;
    }
    __syncthreads();

    for (int i = 0; i < segn; i++) {
        float4 c = lds[i];
        int n = n0 + i;
#pragma unroll
        for (int j = 0; j < QT; j++) {
            float t  = fmaf(qx[j], c.x, fmaf(qy[j], c.y, qz[j] * c.z));
            float d2 = fmaf(-2.0f, t, qc2[j] + c.w);
            // exclude too-close (d2 < thresh^2 covers clamped-negative case);
            // invalid verts have d2 = +inf -> never strictly less than best.
            bool ok = (d2 >= MIN_T2) && (d2 < bd[j]);
            bd[j] = ok ? d2 : bd[j];
            bi[j] = ok ? n  : bi[j];
        }
    }

#pragma unroll
    for (int j = 0; j < QT; j++) {
        int m = m0 + j * TPB;
        unsigned long long key =
            ((unsigned long long)__float_as_uint(bd[j]) << 32) | (unsigned)bi[j];
        atomicMin(&packed[(size_t)b * MM + m], key);
    }
}

// Kernel 3: per-query finalize (gather target, match/near, contribution),
// block-level reduction to 128 partials.
__global__ __launch_bounds__(256) void finalize_kernel(
    const unsigned long long* __restrict__ packed,
    const int* __restrict__ smpl_idx, const float* __restrict__ sdf,
    const int* __restrict__ cloth_idx, const float* __restrict__ sdf_thresh,
    const float* __restrict__ dist_thresh,
    float* __restrict__ blockSums, int* __restrict__ blockMatch)
{
    int q = blockIdx.x * 256 + threadIdx.x;   // 128 blocks x 256 = BB*MM
    int b = q >> 13;                          // q / MM
    unsigned long long key = packed[q];
    float d2  = __uint_as_float((unsigned)(key >> 32));
    int   idx = (int)(unsigned)(key & 0xFFFFFFFFu);
    float nnd = sqrtf(d2);                    // inf if no qualified candidate

    int target = smpl_idx[b * NN + idx];
    int ci0 = cloth_idx[0], ci1 = cloth_idx[1];
    bool match = (target == ci0) || (target == ci1);
    bool near_ = nnd < dist_thresh[0];
    float s = sdf[q];
    float contrib = near_ ? (match ? fabsf(s) : fabsf(s - sdf_thresh[0])) : 0.0f;
    int mt = match ? 1 : 0;

    for (int off = 32; off > 0; off >>= 1) {
        contrib += __shfl_down(contrib, off, 64);
        mt      |= __shfl_down(mt, off, 64);
    }
    __shared__ float wsum[4];
    __shared__ int   wmat[4];
    int wave = threadIdx.x >> 6;
    if ((threadIdx.x & 63) == 0) { wsum[wave] = contrib; wmat[wave] = mt; }
    __syncthreads();
    if (threadIdx.x == 0) {
        blockSums[blockIdx.x]  = wsum[0] + wsum[1] + wsum[2] + wsum[3];
        blockMatch[blockIdx.x] = wmat[0] | wmat[1] | wmat[2] | wmat[3];
    }
}

// Kernel 4: final per-batch reduction (32 partials each) -> loss[b]
__global__ __launch_bounds__(64) void reduce_kernel(
    const float* __restrict__ bs, const int* __restrict__ bm,
    float* __restrict__ out)
{
    int b = blockIdx.x;
    int t = threadIdx.x;
    float s = (t < 32) ? bs[b * 32 + t] : 0.0f;
    int   m = (t < 32) ? bm[b * 32 + t] : 0;
    for (int off = 32; off > 0; off >>= 1) {
        s += __shfl_down(s, off, 64);
        m |= __shfl_down(m, off, 64);
    }
    if (t == 0) out[b] = s * (1.0f / (float)MM) * (m ? 1.0f : 0.0f);
}

extern "C" void kernel_launch(void* const* d_in, const int* in_sizes, int n_in,
                              void* d_out, int out_size, void* d_ws, size_t ws_size,
                              hipStream_t stream)
{
    const float* sdf         = (const float*)d_in[0];
    const float* cloth       = (const float*)d_in[1];
    const int*   smpl_idx    = (const int*)d_in[2];
    const int*   valid       = (const int*)d_in[3];
    const int*   cloth_idx   = (const int*)d_in[4];
    const float* sdf_thresh  = (const float*)d_in[5];
    const float* dist_thresh = (const float*)d_in[6];
    const float* vt          = (const float*)d_in[7];

    char* ws = (char*)d_ws;
    float4* cand                 = (float4*)ws;
    unsigned long long* packed   = (unsigned long long*)(ws + OFF_PACKED);
    float* blockSums             = (float*)(ws + OFF_BSUMS);
    int*   blockMatch            = (int*)(ws + OFF_BMATCH);

    prep_kernel<<<128, 256, 0, stream>>>(vt, valid, cand, packed);
    nn_kernel<<<BB * CHUNKS * NSEG, TPB, 0, stream>>>(cloth, cand, packed);
    finalize_kernel<<<(BB * MM) / 256, 256, 0, stream>>>(
        packed, smpl_idx, sdf, cloth_idx, sdf_thresh, dist_thresh,
        blockSums, blockMatch);
    reduce_kernel<<<BB, 64, 0, stream>>>(blockSums, blockMatch, (float*)d_out);
}

// Round 2
// 120.542 us; speedup vs baseline: 1.0997x; 1.0997x over previous
//
#include <hip/hip_runtime.h>
#include <cstdint>
#include <cstddef>

// Problem constants (match reference file)
#define BB 4
#define MM 8192
#define NN 6890
#define NSEG 64
#define SEGN 108          // ceil(6890/64); last segment has 86
#define CHUNKS 4          // MM / MQ
#define MQ 2048           // queries per nn block
#define QT 8              // queries per thread
#define TPB 256

static constexpr float MIN_T2 = 0.005f * 0.005f;   // MIN_DIST_THRESH^2

// ws layout (bytes):
//   [0, 262144)          u64 packed[BB*MM]   (d2_bits<<32 | idx), atomicMin
//   [262144, 262656)     float blockSums[128]
//   [262656, 263168)     int   blockMatch[128]
#define OFF_BSUMS  262144
#define OFF_BMATCH 262656

// Kernel 0: init packed argmin array to u64-max.
__global__ __launch_bounds__(256) void init_kernel(
    unsigned long long* __restrict__ packed)
{
    int i = blockIdx.x * 256 + threadIdx.x;
    if (i < BB * MM) packed[i] = ~0ULL;
}

// Kernel 1: brute-force NN over one (batch, m-chunk, n-segment) per block.
// Candidate prep fused: each block builds its LDS tile (-2x,-2y,-2z, s2/+inf)
// from v_template + valid directly. Inner loop runs in shifted space
// e = s2 - 2 c.s (3 FMAs/pair); filter via per-query tmin = MIN_T2 - qc2.
__global__ __launch_bounds__(TPB) void nn_kernel(
    const float* __restrict__ cloth, const float* __restrict__ vt,
    const int* __restrict__ valid, unsigned long long* __restrict__ packed)
{
    __shared__ float4 lds[SEGN];
    int bid   = blockIdx.x;            // 1024 blocks
    int seg   = bid & (NSEG - 1);
    int chunk = (bid >> 6) & (CHUNKS - 1);
    int b     = bid >> 8;
    int n0    = seg * SEGN;
    int segn  = (NN - n0 < SEGN) ? (NN - n0) : SEGN;

    // fused candidate prep (one pass, 108 <= 256 threads)
    if (threadIdx.x < segn) {
        int n = n0 + threadIdx.x;
        const float* p = vt + ((size_t)b * NN + n) * 3;
        float x = p[0], y = p[1], z = p[2];
        float s2 = x * x + y * y + z * z;
        if (valid[b * NN + n] <= 0) s2 = __builtin_inff();
        lds[threadIdx.x] = make_float4(-2.0f * x, -2.0f * y, -2.0f * z, s2);
    }

    float qx[QT], qy[QT], qz[QT], tmin[QT], bd[QT];
    int bi[QT];
    int m0 = chunk * MQ + threadIdx.x;
#pragma unroll
    for (int j = 0; j < QT; j++) {
        int m = m0 + j * TPB;
        const float* p = cloth + ((size_t)b * MM + m) * 3;
        float x = p[0], y = p[1], z = p[2];
        qx[j] = x; qy[j] = y; qz[j] = z;
        tmin[j] = MIN_T2 - (x * x + y * y + z * z);  // e >= tmin <=> d2 >= MIN_T2
        bd[j] = __builtin_inff();
        bi[j] = 0;
    }
    __syncthreads();

#pragma unroll 2
    for (int i = 0; i < segn; i++) {
        float4 c = lds[i];
        int n = n0 + i;
#pragma unroll
        for (int j = 0; j < QT; j++) {
            // e = s2 - 2 c.s  (= d2 - qc2, order-preserving per query)
            float e = fmaf(c.x, qx[j], fmaf(c.y, qy[j], fmaf(c.z, qz[j], c.w)));
            bool ok = (e >= tmin[j]) && (e < bd[j]);
            bd[j] = ok ? e : bd[j];
            bi[j] = ok ? n : bi[j];
        }
    }

#pragma unroll
    for (int j = 0; j < QT; j++) {
        int m = m0 + j * TPB;
        float qc2 = MIN_T2 - tmin[j];
        float d2 = bd[j] + qc2;                      // +inf stays +inf
        unsigned long long key =
            ((unsigned long long)__float_as_uint(d2) << 32) | (unsigned)bi[j];
        unsigned long long* p = &packed[(size_t)b * MM + m];
        // hint read: stale values are always >= truth (keys only decrease),
        // so skipping when key >= cur is safe; atomicMin is authoritative.
        unsigned long long cur = *p;
        if (key < cur) atomicMin(p, key);
    }
}

// Kernel 2: per-query finalize (gather target, match/near, contribution),
// block-level reduction to 128 partials.
__global__ __launch_bounds__(256) void finalize_kernel(
    const unsigned long long* __restrict__ packed,
    const int* __restrict__ smpl_idx, const float* __restrict__ sdf,
    const int* __restrict__ cloth_idx, const float* __restrict__ sdf_thresh,
    const float* __restrict__ dist_thresh,
    float* __restrict__ blockSums, int* __restrict__ blockMatch)
{
    int q = blockIdx.x * 256 + threadIdx.x;   // 128 blocks x 256 = BB*MM
    int b = q >> 13;                          // q / MM
    unsigned long long key = packed[q];
    float d2  = __uint_as_float((unsigned)(key >> 32));
    int   idx = (int)(unsigned)(key & 0xFFFFFFFFu);
    float nnd = sqrtf(d2);                    // inf if no qualified candidate

    int target = smpl_idx[b * NN + idx];
    int ci0 = cloth_idx[0], ci1 = cloth_idx[1];
    bool match = (target == ci0) || (target == ci1);
    bool near_ = nnd < dist_thresh[0];
    float s = sdf[q];
    float contrib = near_ ? (match ? fabsf(s) : fabsf(s - sdf_thresh[0])) : 0.0f;
    int mt = match ? 1 : 0;

    for (int off = 32; off > 0; off >>= 1) {
        contrib += __shfl_down(contrib, off, 64);
        mt      |= __shfl_down(mt, off, 64);
    }
    __shared__ float wsum[4];
    __shared__ int   wmat[4];
    int wave = threadIdx.x >> 6;
    if ((threadIdx.x & 63) == 0) { wsum[wave] = contrib; wmat[wave] = mt; }
    __syncthreads();
    if (threadIdx.x == 0) {
        blockSums[blockIdx.x]  = wsum[0] + wsum[1] + wsum[2] + wsum[3];
        blockMatch[blockIdx.x] = wmat[0] | wmat[1] | wmat[2] | wmat[3];
    }
}

// Kernel 3: final per-batch reduction (32 partials each) -> loss[b]
__global__ __launch_bounds__(64) void reduce_kernel(
    const float* __restrict__ bs, const int* __restrict__ bm,
    float* __restrict__ out)
{
    int b = blockIdx.x;
    int t = threadIdx.x;
    float s = (t < 32) ? bs[b * 32 + t] : 0.0f;
    int   m = (t < 32) ? bm[b * 32 + t] : 0;
    for (int off = 32; off > 0; off >>= 1) {
        s += __shfl_down(s, off, 64);
        m |= __shfl_down(m, off, 64);
    }
    if (t == 0) out[b] = s * (1.0f / (float)MM) * (m ? 1.0f : 0.0f);
}

extern "C" void kernel_launch(void* const* d_in, const int* in_sizes, int n_in,
                              void* d_out, int out_size, void* d_ws, size_t ws_size,
                              hipStream_t stream)
{
    const float* sdf         = (const float*)d_in[0];
    const float* cloth       = (const float*)d_in[1];
    const int*   smpl_idx    = (const int*)d_in[2];
    const int*   valid       = (const int*)d_in[3];
    const int*   cloth_idx   = (const int*)d_in[4];
    const float* sdf_thresh  = (const float*)d_in[5];
    const float* dist_thresh = (const float*)d_in[6];
    const float* vt          = (const float*)d_in[7];

    char* ws = (char*)d_ws;
    unsigned long long* packed   = (unsigned long long*)ws;
    float* blockSums             = (float*)(ws + OFF_BSUMS);
    int*   blockMatch            = (int*)(ws + OFF_BMATCH);

    init_kernel<<<128, 256, 0, stream>>>(packed);
    nn_kernel<<<BB * CHUNKS * NSEG, TPB, 0, stream>>>(cloth, vt, valid, packed);
    finalize_kernel<<<(BB * MM) / 256, 256, 0, stream>>>(
        packed, smpl_idx, sdf, cloth_idx, sdf_thresh, dist_thresh,
        blockSums, blockMatch);
    reduce_kernel<<<BB, 64, 0, stream>>>(blockSums, blockMatch, (float*)d_out);
}